// Round 5
// baseline (612.604 us; speedup 1.0000x reference)
//
#include <hip/hip_runtime.h>
#include <float.h>
#include <math.h>

#define TOKS 16384
#define HDIM 4096
#define NEXP 64
#define TB   64                 // tokens per block
#define HC   16                 // h per chunk
#define NWAVE 8
#define HSLICE (HDIM / NWAVE)   // 512 h per wave
#define NCH (HSLICE / HC)       // 32 chunks

// Block: 512 thr = 8 waves. Block tile 64 tok x 64 exp; wave wv owns h in
// [wv*512, wv*512+512). Lane (tx=lane&7, ey=lane>>3) owns an 8 tok x 8 exp
// register tile (64 acc VGPRs).
// R2-R4: compiler pinned 128 VGPR (launch_bounds 2nd arg is a no-op here:
// (512,2) and (512,1) gave identical binaries) -> ~60-reg spill -> 1.3 GB
// scratch write traffic dominated. Fix: amdgpu_waves_per_eu(2,2) = hard
// 256-VGPR budget (matches the 2 waves/EU that 128 KiB LDS forces anyway),
// plus sched_barrier(0) every 4 h-steps to cap operand-hoist pressure.
__global__ __launch_bounds__(512)
__attribute__((amdgpu_waves_per_eu(2, 2)))
void topk_router_kernel(const float* __restrict__ x,
                        const float* __restrict__ wgt,
                        const float* __restrict__ bias,
                        float* __restrict__ out)
{
  __shared__ __align__(16) float smem[32768];   // 128 KiB
  const int tid  = threadIdx.x;
  const int lane = tid & 63;
  const int wv   = tid >> 6;
  const int tokBase = blockIdx.x * TB;

  float* const slab = smem + wv * 4096;   // 16 KiB per wave
  float* const xs0 = slab;                // [16 h][64 tok]
  float* const ws0 = slab + 1024;         // [16 h][64 exp]
  float* const xs1 = slab + 2048;
  float* const ws1 = slab + 3072;

  const int tx = lane & 7;          // token-group in compute
  const int ey = lane >> 3;         // expert-group in compute
  const int sa = lane & 31;         // staging: rows 2sa, 2sa+1
  const int sh = (lane >> 5) * 8;   // staging: h-offset 0 or 8

  const int hbase = wv * HSLICE;
  const float* const xg = x   + (size_t)(tokBase + 2 * sa) * HDIM + hbase + sh;
  const float* const wg = wgt + (size_t)(2 * sa) * HDIM + hbase + sh;

  float acc[64];
#pragma unroll
  for (int i = 0; i < 64; ++i) acc[i] = 0.f;

  float4 rxa, rxb, rxc, rxd, rwa, rwb, rwc, rwd;

#define LOADC(c) do { \
    const float* p_ = xg + (c) * HC; \
    rxa = *(const float4*)(p_);           rxb = *(const float4*)(p_ + 4); \
    rxc = *(const float4*)(p_ + HDIM);    rxd = *(const float4*)(p_ + HDIM + 4); \
    const float* q_ = wg + (c) * HC; \
    rwa = *(const float4*)(q_);           rwb = *(const float4*)(q_ + 4); \
    rwc = *(const float4*)(q_ + HDIM);    rwd = *(const float4*)(q_ + HDIM + 4); \
  } while (0)

#define ST2(dst, a, b) *(float2*)(dst) = make_float2((a), (b))

  // transpose-write staged regs into LDS [h][row]: 16 ds_write_b64, 2-way banks
#define WRITEC(xs, ws) do { \
    float* xr_ = (xs) + sh * 64 + 2 * sa; \
    ST2(xr_ + 0 * 64, rxa.x, rxc.x); ST2(xr_ + 1 * 64, rxa.y, rxc.y); \
    ST2(xr_ + 2 * 64, rxa.z, rxc.z); ST2(xr_ + 3 * 64, rxa.w, rxc.w); \
    ST2(xr_ + 4 * 64, rxb.x, rxd.x); ST2(xr_ + 5 * 64, rxb.y, rxd.y); \
    ST2(xr_ + 6 * 64, rxb.z, rxd.z); ST2(xr_ + 7 * 64, rxb.w, rxd.w); \
    float* wr_ = (ws) + sh * 64 + 2 * sa; \
    ST2(wr_ + 0 * 64, rwa.x, rwc.x); ST2(wr_ + 1 * 64, rwa.y, rwc.y); \
    ST2(wr_ + 2 * 64, rwa.z, rwc.z); ST2(wr_ + 3 * 64, rwa.w, rwc.w); \
    ST2(wr_ + 4 * 64, rwb.x, rwd.x); ST2(wr_ + 5 * 64, rwb.y, rwd.y); \
    ST2(wr_ + 6 * 64, rwb.z, rwd.z); ST2(wr_ + 7 * 64, rwb.w, rwd.w); \
  } while (0)

  // 8 FMAs against one broadcast x value; all acc indices compile-time const
#define FMA8(b, xval) \
    acc[(b)+0] = fmaf((xval), wa_.x, acc[(b)+0]); \
    acc[(b)+1] = fmaf((xval), wa_.y, acc[(b)+1]); \
    acc[(b)+2] = fmaf((xval), wa_.z, acc[(b)+2]); \
    acc[(b)+3] = fmaf((xval), wa_.w, acc[(b)+3]); \
    acc[(b)+4] = fmaf((xval), wb_.x, acc[(b)+4]); \
    acc[(b)+5] = fmaf((xval), wb_.y, acc[(b)+5]); \
    acc[(b)+6] = fmaf((xval), wb_.z, acc[(b)+6]); \
    acc[(b)+7] = fmaf((xval), wb_.w, acc[(b)+7]);

  // 16 h-steps: per h 4 ds_read_b128 (broadcast/2-way) + 64 fmaf.
  // sched_barrier(0) every 4 steps: cap ds_read hoisting -> bounded pressure.
#define FMAC(xs, ws) do { \
    _Pragma("unroll") \
    for (int h = 0; h < HC; ++h) { \
      const float4 xa_ = *(const float4*)((xs) + h * 64 + tx * 8); \
      const float4 xb_ = *(const float4*)((xs) + h * 64 + tx * 8 + 4); \
      const float4 wa_ = *(const float4*)((ws) + h * 64 + ey * 8); \
      const float4 wb_ = *(const float4*)((ws) + h * 64 + ey * 8 + 4); \
      FMA8(0,  xa_.x) FMA8(8,  xa_.y) FMA8(16, xa_.z) FMA8(24, xa_.w) \
      FMA8(32, xb_.x) FMA8(40, xb_.y) FMA8(48, xb_.z) FMA8(56, xb_.w) \
      if ((h & 3) == 3) __builtin_amdgcn_sched_barrier(0); \
    } \
  } while (0)

  // ---- software-pipelined main loop: no __syncthreads(), wave-private bufs ----
  LOADC(0);
  WRITEC(xs0, ws0);
  LOADC(1);
  for (int c = 0; c < NCH; c += 2) {
    WRITEC(xs1, ws1);                    // chunk c+1 regs -> LDS
    if (c + 2 < NCH) LOADC(c + 2);       // prefetch chunk c+2
    FMAC(xs0, ws0);                      // compute chunk c
    if (c + 2 < NCH) WRITEC(xs0, ws0);   // chunk c+2 regs -> LDS
    if (c + 3 < NCH) LOADC(c + 3);       // prefetch chunk c+3
    FMAC(xs1, ws1);                      // compute chunk c+1
  }

  // ---- cross-wave reduction: red[p][64 tok][64 e], p=0..3 aliases slabs ----
#define TILE_W(plane) do { \
    float* rp_ = smem + (plane) * 4096 + ey * 8; \
    _Pragma("unroll") \
    for (int i_ = 0; i_ < 8; ++i_) { \
      float* q_ = rp_ + (tx * 8 + i_) * 64; \
      *(float4*)(q_)     = make_float4(acc[i_*8+0], acc[i_*8+1], acc[i_*8+2], acc[i_*8+3]); \
      *(float4*)(q_ + 4) = make_float4(acc[i_*8+4], acc[i_*8+5], acc[i_*8+6], acc[i_*8+7]); \
    } \
  } while (0)

  __syncthreads();                       // all waves done reading their slabs
  if (wv >= 4) TILE_W(wv - 4);           // waves 4..7 write partial plane
  __syncthreads();
  if (wv < 4) {                          // waves 0..3: acc += plane, write back
    const float* rp = smem + wv * 4096 + ey * 8;
#pragma unroll
    for (int i = 0; i < 8; ++i) {
      const float4 a = *(const float4*)(rp + (tx * 8 + i) * 64);
      const float4 b = *(const float4*)(rp + (tx * 8 + i) * 64 + 4);
      acc[i*8+0] += a.x; acc[i*8+1] += a.y; acc[i*8+2] += a.z; acc[i*8+3] += a.w;
      acc[i*8+4] += b.x; acc[i*8+5] += b.y; acc[i*8+6] += b.z; acc[i*8+7] += b.w;
    }
    TILE_W(wv);
  }
  __syncthreads();
  // ---- final 4-plane sum + bias -> fin[64][64] at smem+16384 (slab 4, free) ----
  {
    const int t  = tid >> 3;
    const int e0 = (tid & 7) * 8;
    float4 s0 = *(const float4*)&bias[e0];
    float4 s1 = *(const float4*)&bias[e0 + 4];
#pragma unroll
    for (int p = 0; p < 4; ++p) {
      const float4 a = *(const float4*)&smem[p * 4096 + t * 64 + e0];
      const float4 b = *(const float4*)&smem[p * 4096 + t * 64 + e0 + 4];
      s0.x += a.x; s0.y += a.y; s0.z += a.z; s0.w += a.w;
      s1.x += b.x; s1.y += b.y; s1.z += b.z; s1.w += b.w;
    }
    *(float4*)&smem[16384 + t * 64 + e0]     = s0;
    *(float4*)&smem[16384 + t * 64 + e0 + 4] = s1;
  }
  __syncthreads();

  // ---- top-8 + softmax: wave wv handles tokens wv*8 .. wv*8+7 ----
  const float* fin = smem + 16384;
  for (int tt = 0; tt < 8; ++tt) {
    const int t = wv * 8 + tt;
    float v = fin[t * 64 + lane];        // lane = expert id
    float myval = 0.f, m0 = 0.f;
    int myidx = 0;
#pragma unroll
    for (int k = 0; k < 8; ++k) {
      float bv = v;
      int   bi = lane;
#pragma unroll
      for (int off = 1; off < 64; off <<= 1) {   // argmax, min-index tiebreak
        const float ov = __shfl_xor(bv, off);
        const int   oi = __shfl_xor(bi, off);
        if (ov > bv || (ov == bv && oi < bi)) { bv = ov; bi = oi; }
      }
      if (k == 0) m0 = bv;
      if (lane == k) { myval = bv; myidx = bi; }
      if (lane == bi) v = -FLT_MAX;      // bi is wave-uniform
    }
    const float el = (lane < 8) ? expf(myval - m0) : 0.f;
    float ssum = el;
    ssum += __shfl_xor(ssum, 1);
    ssum += __shfl_xor(ssum, 2);
    ssum += __shfl_xor(ssum, 4);
    if (lane < 8) {
      const size_t tg = (size_t)(tokBase + t);
      out[tg * 8 + lane] = el / ssum;                        // weights (f32)
      out[(size_t)TOKS * 8 + tg * 8 + lane] = (float)myidx;  // indices as f32
    }
  }
}

extern "C" void kernel_launch(void* const* d_in, const int* in_sizes, int n_in,
                              void* d_out, int out_size, void* d_ws, size_t ws_size,
                              hipStream_t stream) {
  const float* x    = (const float*)d_in[0];
  const float* wgt  = (const float*)d_in[1];
  const float* bias = (const float*)d_in[2];
  float* out = (float*)d_out;
  hipLaunchKernelGGL(topk_router_kernel, dim3(TOKS / TB), dim3(512), 0, stream,
                     x, wgt, bias, out);
}

// Round 6
// 261.970 us; speedup vs baseline: 2.3385x; 2.3385x over previous
//
#include <hip/hip_runtime.h>
#include <float.h>
#include <math.h>

#define TOKS 16384
#define HDIM 4096
#define NEXP 64
#define TB   64                  // tokens per block
#define HC   16                  // h per chunk
#define HSLICE 1024              // h per wave (4 H-slices)
#define NCH (HSLICE / HC)        // 64 chunks

// Block: 512 thr = 8 waves; block tile 64 tok x 64 exp.
// wv = eh*4 + hs: hs = H-slice (4 x 1024h), eh = expert half (2 x 32e).
// Lane (tx=lane&15, ey=lane>>4) owns 4 tok x 8 exp = 32 acc VGPRs.
// R2-R5 lesson: compiler pins VGPR=128 regardless of launch_bounds /
// waves_per_eu; 64-acc tile structurally needs ~126+hoist -> wholesale acc
// spill (1.3GB scratch traffic = the entire 610us). This tile needs ~82 regs
// (+<=48 hoist window bounded by sched_barrier every 4 h) -> fits 128.
// Per h: 3 ds_read_b128 (2-way/broadcast, free) -> 32 FMAs.
// Per-wave PRIVATE double-buffered LDS staging -> zero barriers in main loop.
__global__ __launch_bounds__(512)
void topk_router_kernel(const float* __restrict__ x,
                        const float* __restrict__ wgt,
                        const float* __restrict__ bias,
                        float* __restrict__ out)
{
  __shared__ __align__(16) float smem[24576];   // 96 KiB
  const int tid  = threadIdx.x;
  const int lane = tid & 63;
  const int wv   = tid >> 6;
  const int hs   = wv & 3;
  const int eh   = wv >> 2;
  const int tokBase = blockIdx.x * TB;

  float* const slab = smem + wv * 3072;   // 12 KiB per wave
  float* const xs0 = slab;                // [16 h][64 tok]
  float* const ws0 = slab + 1024;         // [16 h][32 exp]
  float* const xs1 = slab + 1536;
  float* const ws1 = slab + 2560;

  const int tx = lane & 15;         // token group (4 toks)
  const int ey = lane >> 4;         // expert sub-group (8 exps)
  const int le = lane & 31;         // staging: expert row
  const int lh = (lane >> 5) * 8;   // staging: h-offset 0 or 8

  const int hbase = hs * HSLICE;
  const float* const xg = x   + (size_t)(tokBase + lane) * HDIM + hbase;
  const float* const wg = wgt + (size_t)(eh * 32 + le) * HDIM + hbase + lh;

  float acc[32];
#pragma unroll
  for (int i = 0; i < 32; ++i) acc[i] = 0.f;

  float4 rx0, rx1, rx2, rx3, rw0, rw1;

  // 6 global b128 loads for chunk c: x = 1 token-row x 16h, w = 1 exp-row x 8h
#define LOADC(c) do { \
    const float* p_ = xg + (c) * HC; \
    rx0 = *(const float4*)(p_);      rx1 = *(const float4*)(p_ + 4); \
    rx2 = *(const float4*)(p_ + 8);  rx3 = *(const float4*)(p_ + 12); \
    const float* q_ = wg + (c) * HC; \
    rw0 = *(const float4*)(q_);      rw1 = *(const float4*)(q_ + 4); \
  } while (0)

  // transpose-write into LDS [h][row]: 24 ds_write_b32, 2-way banks (free)
#define WRITEC(xs, ws) do { \
    float* xr_ = (xs) + lane; \
    xr_[ 0*64] = rx0.x; xr_[ 1*64] = rx0.y; xr_[ 2*64] = rx0.z; xr_[ 3*64] = rx0.w; \
    xr_[ 4*64] = rx1.x; xr_[ 5*64] = rx1.y; xr_[ 6*64] = rx1.z; xr_[ 7*64] = rx1.w; \
    xr_[ 8*64] = rx2.x; xr_[ 9*64] = rx2.y; xr_[10*64] = rx2.z; xr_[11*64] = rx2.w; \
    xr_[12*64] = rx3.x; xr_[13*64] = rx3.y; xr_[14*64] = rx3.z; xr_[15*64] = rx3.w; \
    float* wr_ = (ws) + lh * 32 + le; \
    wr_[0*32] = rw0.x; wr_[1*32] = rw0.y; wr_[2*32] = rw0.z; wr_[3*32] = rw0.w; \
    wr_[4*32] = rw1.x; wr_[5*32] = rw1.y; wr_[6*32] = rw1.z; wr_[7*32] = rw1.w; \
  } while (0)

  // 8 FMAs against one broadcast x value
#define FMA8(b, xval) \
    acc[(b)+0] = fmaf((xval), wa_.x, acc[(b)+0]); \
    acc[(b)+1] = fmaf((xval), wa_.y, acc[(b)+1]); \
    acc[(b)+2] = fmaf((xval), wa_.z, acc[(b)+2]); \
    acc[(b)+3] = fmaf((xval), wa_.w, acc[(b)+3]); \
    acc[(b)+4] = fmaf((xval), wb_.x, acc[(b)+4]); \
    acc[(b)+5] = fmaf((xval), wb_.y, acc[(b)+5]); \
    acc[(b)+6] = fmaf((xval), wb_.z, acc[(b)+6]); \
    acc[(b)+7] = fmaf((xval), wb_.w, acc[(b)+7]);

  // 16 h-steps: per h 3 ds_read_b128 (2-way/broadcast) + 32 fmaf.
  // sched_barrier every 4 h bounds operand hoisting (~48 regs max window).
#define FMAC(xs, ws) do { \
    _Pragma("unroll") \
    for (int h = 0; h < HC; ++h) { \
      const float4 xa_ = *(const float4*)((xs) + h * 64 + tx * 4); \
      const float4 wa_ = *(const float4*)((ws) + h * 32 + ey * 8); \
      const float4 wb_ = *(const float4*)((ws) + h * 32 + ey * 8 + 4); \
      FMA8(0, xa_.x) FMA8(8, xa_.y) FMA8(16, xa_.z) FMA8(24, xa_.w) \
      if ((h & 3) == 3) __builtin_amdgcn_sched_barrier(0); \
    } \
  } while (0)

  // ---- software-pipelined main loop: no __syncthreads(), wave-private bufs ----
  LOADC(0);
  WRITEC(xs0, ws0);
  LOADC(1);
  for (int c = 0; c < NCH; c += 2) {
    WRITEC(xs1, ws1);                    // chunk c+1 regs -> LDS
    if (c + 2 < NCH) LOADC(c + 2);       // prefetch chunk c+2
    FMAC(xs0, ws0);                      // compute chunk c
    if (c + 2 < NCH) WRITEC(xs0, ws0);   // chunk c+2 regs -> LDS
    if (c + 3 < NCH) LOADC(c + 3);       // prefetch chunk c+3
    FMAC(xs1, ws1);                      // compute chunk c+1
  }

  // ---- reduction: plane[wv][64 tok][32 exp] aliases slabs, sum over hs ----
  __syncthreads();                       // all waves done with their slabs
  {
    float* pl = smem + wv * 2048 + ey * 8;
#pragma unroll
    for (int i = 0; i < 4; ++i) {
      float* q = pl + (tx * 4 + i) * 32;
      *(float4*)(q)     = make_float4(acc[i*8+0], acc[i*8+1], acc[i*8+2], acc[i*8+3]);
      *(float4*)(q + 4) = make_float4(acc[i*8+4], acc[i*8+5], acc[i*8+6], acc[i*8+7]);
    }
  }
  __syncthreads();
  // ---- final sum over 4 H-planes + bias -> fin[64][64] at smem+16384 ----
  {
    const int t   = tid >> 3;            // 0..63
    const int e0  = (tid & 7) * 8;       // 0..56
    const int pb  = (e0 >> 5) * 4;       // plane base = eh*4
    const int el  = e0 & 31;
    float4 s0 = *(const float4*)&bias[e0];
    float4 s1 = *(const float4*)&bias[e0 + 4];
#pragma unroll
    for (int p = 0; p < 4; ++p) {
      const float* q = &smem[(pb + p) * 2048 + t * 32 + el];
      const float4 a = *(const float4*)(q);
      const float4 b = *(const float4*)(q + 4);
      s0.x += a.x; s0.y += a.y; s0.z += a.z; s0.w += a.w;
      s1.x += b.x; s1.y += b.y; s1.z += b.z; s1.w += b.w;
    }
    *(float4*)&smem[16384 + t * 64 + e0]     = s0;
    *(float4*)&smem[16384 + t * 64 + e0 + 4] = s1;
  }
  __syncthreads();

  // ---- top-8 + softmax: wave wv handles tokens wv*8 .. wv*8+7 ----
  const float* fin = smem + 16384;
  for (int tt = 0; tt < 8; ++tt) {
    const int t = wv * 8 + tt;
    float v = fin[t * 64 + lane];        // lane = expert id
    float myval = 0.f, m0 = 0.f;
    int myidx = 0;
#pragma unroll
    for (int k = 0; k < 8; ++k) {
      float bv = v;
      int   bi = lane;
#pragma unroll
      for (int off = 1; off < 64; off <<= 1) {   // argmax, min-index tiebreak
        const float ov = __shfl_xor(bv, off);
        const int   oi = __shfl_xor(bi, off);
        if (ov > bv || (ov == bv && oi < bi)) { bv = ov; bi = oi; }
      }
      if (k == 0) m0 = bv;
      if (lane == k) { myval = bv; myidx = bi; }
      if (lane == bi) v = -FLT_MAX;      // bi is wave-uniform
    }
    const float el = (lane < 8) ? expf(myval - m0) : 0.f;
    float ssum = el;
    ssum += __shfl_xor(ssum, 1);
    ssum += __shfl_xor(ssum, 2);
    ssum += __shfl_xor(ssum, 4);
    if (lane < 8) {
      const size_t tg = (size_t)(tokBase + t);
      out[tg * 8 + lane] = el / ssum;                        // weights (f32)
      out[(size_t)TOKS * 8 + tg * 8 + lane] = (float)myidx;  // indices as f32
    }
  }
}

extern "C" void kernel_launch(void* const* d_in, const int* in_sizes, int n_in,
                              void* d_out, int out_size, void* d_ws, size_t ws_size,
                              hipStream_t stream) {
  const float* x    = (const float*)d_in[0];
  const float* wgt  = (const float*)d_in[1];
  const float* bias = (const float*)d_in[2];
  float* out = (float*)d_out;
  hipLaunchKernelGGL(topk_router_kernel, dim3(TOKS / TB), dim3(512), 0, stream,
                     x, wgt, bias, out);
}

// Round 8
// 170.973 us; speedup vs baseline: 3.5831x; 1.5322x over previous
//
#include <hip/hip_runtime.h>
#include <float.h>
#include <math.h>

#define TOKS 16384
#define HDIM 4096
#define NEXP 64
#define BM   64          // tokens per block
#define BK   64          // k per chunk
#define NCH  (HDIM / BK) // 64 chunks

typedef __attribute__((ext_vector_type(8)))  short short8v;  // 8 bf16 (A/B frag)
typedef __attribute__((ext_vector_type(16))) float f32x16;   // C/D frag

// Exact 3-way bf16 split by truncation: v = s1 + s2 + s3 + eps, eps <= 2^-24*|v|.
// (fp32 mantissa 24 = 3 x 8-bit bf16 mantissas; each residual subtraction exact.)
__device__ __forceinline__ void split3(float v, unsigned& b1, unsigned& b2, unsigned& b3) {
  unsigned xb = __float_as_uint(v);
  b1 = xb >> 16;
  float r = v - __uint_as_float(xb & 0xFFFF0000u);
  unsigned rb = __float_as_uint(r);
  b2 = rb >> 16;
  float r2 = r - __uint_as_float(rb & 0xFFFF0000u);
  b3 = __float_as_uint(r2) >> 16;
}

// two elems -> one packed u32 per split plane
__device__ __forceinline__ void cvt2(float a, float b, unsigned& o1, unsigned& o2, unsigned& o3) {
  unsigned a1, a2, a3, c1, c2, c3;
  split3(a, a1, a2, a3);
  split3(b, c1, c2, c3);
  o1 = a1 | (c1 << 16); o2 = a2 | (c2 << 16); o3 = a3 | (c3 << 16);
}

// ---- block 256 thr = 4 waves, tile 64 tok x 64 exp, K-chunks of 64 ----
// Wave (wm=wv>>1, we=wv&1) owns 32tok x 32exp via mfma_f32_32x32x16_bf16.
// 6 MFMA per K16 step. Error budget (vs np fp32): x1w1 into acc_m0/m1
// (2-way split, depth 128 each); 5 cross terms (<=2^-8 rel) into acc_c.
// eps ~ 3e-7 < the ~5e-7 band the passing fp32 kernels sat in.
// LDS tiles [row][k] bf16 128B rows, granule-XOR swizzle g^(row&7); both x and
// w split in-kernel from fp32 during staging (no pre-kernel, no d_ws).
// LDS: 2 x 48KB staging + 16KB fin = 112KB -> 1 block/CU, 4 waves.
__global__ __launch_bounds__(256)
void router_mfma_kernel(const float* __restrict__ x,
                        const float* __restrict__ wgt,
                        const float* __restrict__ bias,
                        float* __restrict__ out) {
  __shared__ __align__(16) unsigned char smem[114688];
  const int tid  = threadIdx.x;
  const int lane = tid & 63;
  const int wv   = tid >> 6;
  const int tokBase = blockIdx.x * BM;

  // staging: thread owns row stok (x-token and w-expert), k-seg of 16 floats
  const int stok = tid >> 2;
  const int seg  = tid & 3;
  const unsigned swz0 = (unsigned)(((seg * 2)     ^ (stok & 7)) << 4);
  const unsigned swz1 = (unsigned)(((seg * 2 + 1) ^ (stok & 7)) << 4);
  const int rowbyte_s = stok * 128;
  const float* const xrow = x   + (size_t)(tokBase + stok) * HDIM;
  const float* const wrow = wgt + (size_t)stok * HDIM;

  // compute: wave tile + frag lane mapping (row/col = lane&31, k per lane>>5)
  const int wm = wv >> 1, we = wv & 1;
  const int r  = lane & 31, h2 = lane >> 5;
  const int r7 = r & 7;
  const int byteA = (wm * 32 + r) * 128;
  const int byteB = (we * 32 + r) * 128;

  f32x16 acc_m0, acc_m1, acc_c;
#pragma unroll
  for (int i = 0; i < 16; ++i) { acc_m0[i] = 0.f; acc_m1[i] = 0.f; acc_c[i] = 0.f; }

  float4 nf0, nf1, nf2, nf3;   // x chunk (16 f32)
  float4 ng0, ng1, ng2, ng3;   // w chunk (16 f32)

#define GLOAD(c) do { \
    const int kb_ = (c) * BK + seg * 16; \
    nf0 = *(const float4*)(xrow + kb_);      nf1 = *(const float4*)(xrow + kb_ + 4); \
    nf2 = *(const float4*)(xrow + kb_ + 8);  nf3 = *(const float4*)(xrow + kb_ + 12); \
    ng0 = *(const float4*)(wrow + kb_);      ng1 = *(const float4*)(wrow + kb_ + 4); \
    ng2 = *(const float4*)(wrow + kb_ + 8);  ng3 = *(const float4*)(wrow + kb_ + 12); \
  } while (0)

  // split + transpose-write into LDS: 12 ds_write_b128 per thread
#define SWRITE(b) do { \
    unsigned char* bb_ = smem + (b) * 49152; \
    uint4 q1l, q2l, q3l, q1h, q2h, q3h; \
    cvt2(nf0.x, nf0.y, q1l.x, q2l.x, q3l.x); \
    cvt2(nf0.z, nf0.w, q1l.y, q2l.y, q3l.y); \
    cvt2(nf1.x, nf1.y, q1l.z, q2l.z, q3l.z); \
    cvt2(nf1.z, nf1.w, q1l.w, q2l.w, q3l.w); \
    cvt2(nf2.x, nf2.y, q1h.x, q2h.x, q3h.x); \
    cvt2(nf2.z, nf2.w, q1h.y, q2h.y, q3h.y); \
    cvt2(nf3.x, nf3.y, q1h.z, q2h.z, q3h.z); \
    cvt2(nf3.z, nf3.w, q1h.w, q2h.w, q3h.w); \
    *(uint4*)(bb_ +     0 + rowbyte_s + swz0) = q1l; \
    *(uint4*)(bb_ +     0 + rowbyte_s + swz1) = q1h; \
    *(uint4*)(bb_ +  8192 + rowbyte_s + swz0) = q2l; \
    *(uint4*)(bb_ +  8192 + rowbyte_s + swz1) = q2h; \
    *(uint4*)(bb_ + 16384 + rowbyte_s + swz0) = q3l; \
    *(uint4*)(bb_ + 16384 + rowbyte_s + swz1) = q3h; \
    cvt2(ng0.x, ng0.y, q1l.x, q2l.x, q3l.x); \
    cvt2(ng0.z, ng0.w, q1l.y, q2l.y, q3l.y); \
    cvt2(ng1.x, ng1.y, q1l.z, q2l.z, q3l.z); \
    cvt2(ng1.z, ng1.w, q1l.w, q2l.w, q3l.w); \
    cvt2(ng2.x, ng2.y, q1h.x, q2h.x, q3h.x); \
    cvt2(ng2.z, ng2.w, q1h.y, q2h.y, q3h.y); \
    cvt2(ng3.x, ng3.y, q1h.z, q2h.z, q3h.z); \
    cvt2(ng3.z, ng3.w, q1h.w, q2h.w, q3h.w); \
    *(uint4*)(bb_ + 24576 + rowbyte_s + swz0) = q1l; \
    *(uint4*)(bb_ + 24576 + rowbyte_s + swz1) = q1h; \
    *(uint4*)(bb_ + 32768 + rowbyte_s + swz0) = q2l; \
    *(uint4*)(bb_ + 32768 + rowbyte_s + swz1) = q2h; \
    *(uint4*)(bb_ + 40960 + rowbyte_s + swz0) = q3l; \
    *(uint4*)(bb_ + 40960 + rowbyte_s + swz1) = q3h; \
  } while (0)

#define MFMA(a, b, c) __builtin_amdgcn_mfma_f32_32x32x16_bf16((a), (b), (c), 0, 0, 0)

#define COMPUTE(b) do { \
    const unsigned char* bb_ = smem + (b) * 49152; \
    _Pragma("unroll") \
    for (int s = 0; s < 4; ++s) { \
      const int off_ = ((2 * s + h2) ^ r7) << 4; \
      const short8v a1_ = *(const short8v*)(bb_ +     0 + byteA + off_); \
      const short8v b1_ = *(const short8v*)(bb_ + 24576 + byteB + off_); \
      if (s < 2) acc_m0 = MFMA(a1_, b1_, acc_m0); \
      else       acc_m1 = MFMA(a1_, b1_, acc_m1); \
      const short8v a2_ = *(const short8v*)(bb_ +  8192 + byteA + off_); \
      const short8v b2_ = *(const short8v*)(bb_ + 32768 + byteB + off_); \
      acc_c = MFMA(a1_, b2_, acc_c); \
      acc_c = MFMA(a2_, b1_, acc_c); \
      const short8v a3_ = *(const short8v*)(bb_ + 16384 + byteA + off_); \
      const short8v b3_ = *(const short8v*)(bb_ + 40960 + byteB + off_); \
      acc_c = MFMA(a1_, b3_, acc_c); \
      acc_c = MFMA(a2_, b2_, acc_c); \
      acc_c = MFMA(a3_, b1_, acc_c); \
    } \
  } while (0)

  // ---- pipelined K-loop: gload(c+1) | compute(c) | bar | swrite(c+1) | bar ----
  GLOAD(0);
  SWRITE(0);
  __syncthreads();
  for (int c = 0; c < NCH; ++c) {
    if (c < NCH - 1) GLOAD(c + 1);
    COMPUTE(c & 1);
    __syncthreads();
    if (c < NCH - 1) SWRITE((c + 1) & 1);
    __syncthreads();
  }

  // ---- C -> fin[64][64] f32 (row=(reg&3)+8*(reg>>2)+4*h2, col=lane&31) ----
  float* fin = (float*)(smem + 98304);
#pragma unroll
  for (int reg = 0; reg < 16; ++reg) {
    const int rowf = (reg & 3) + 8 * (reg >> 2) + 4 * h2;
    fin[(wm * 32 + rowf) * 64 + we * 32 + r] = (acc_m0[reg] + acc_m1[reg]) + acc_c[reg];
  }
  __syncthreads();

  // ---- top-8 + softmax: wave wv handles tokens wv*16 .. wv*16+15 ----
  for (int tt = 0; tt < 16; ++tt) {
    const int t = wv * 16 + tt;
    float v = fin[t * 64 + lane] + bias[lane];   // lane = expert id
    float myval = 0.f, m0 = 0.f;
    int myidx = 0;
#pragma unroll
    for (int k = 0; k < 8; ++k) {
      float bv = v;
      int   bi = lane;
#pragma unroll
      for (int off = 1; off < 64; off <<= 1) {   // argmax, min-index tiebreak
        const float ov = __shfl_xor(bv, off);
        const int   oi = __shfl_xor(bi, off);
        if (ov > bv || (ov == bv && oi < bi)) { bv = ov; bi = oi; }
      }
      if (k == 0) m0 = bv;
      if (lane == k) { myval = bv; myidx = bi; }
      if (lane == bi) v = -FLT_MAX;              // bi is wave-uniform
    }
    const float el = (lane < 8) ? expf(myval - m0) : 0.f;
    float ssum = el;
    ssum += __shfl_xor(ssum, 1);
    ssum += __shfl_xor(ssum, 2);
    ssum += __shfl_xor(ssum, 4);
    if (lane < 8) {
      const size_t tg = (size_t)(tokBase + t);
      out[tg * 8 + lane] = el / ssum;                        // weights (f32)
      out[(size_t)TOKS * 8 + tg * 8 + lane] = (float)myidx;  // indices as f32
    }
  }
}

extern "C" void kernel_launch(void* const* d_in, const int* in_sizes, int n_in,
                              void* d_out, int out_size, void* d_ws, size_t ws_size,
                              hipStream_t stream) {
  const float* x    = (const float*)d_in[0];
  const float* wgt  = (const float*)d_in[1];
  const float* bias = (const float*)d_in[2];
  float* out = (float*)d_out;
  hipLaunchKernelGGL(router_mfma_kernel, dim3(TOKS / BM), dim3(256), 0, stream,
                     x, wgt, bias, out);
}